// Round 4
// baseline (45.100 us; speedup 1.0000x reference)
//
#include <hip/hip_runtime.h>

#define W 512

// ---------------------------------------------------------------------------
// Fused kernel, 1024 threads = 16 waves per block.
//
// Blocks [0, B*16):  column scan (channel 1). Tile = 32 cols x 512 rows.
//   Thread (col = t&31, seg = t>>5) owns a 16-row segment of one column:
//   16 live registers (no spill), strided-but-coalesced loads (each
//   wave-load = 2 x 128 B contiguous row chunks). Segment totals exchanged
//   via 4 KB LDS; exclusive offset summed per column; single read + single
//   write per element.
//
// Blocks [B*16, ...): row scan (channel 0). One wave per 512-float row.
//   Lane l owns elements [8l, 8l+8) via 2x float4; local scan of 8 +
//   6-step __shfl_up wave scan.
// ---------------------------------------------------------------------------
__global__ __launch_bounds__(1024) void fused_scan_kernel(const float* __restrict__ in,
                                                          float* __restrict__ out,
                                                          int B) {
    __shared__ float sums[32][32];     // [segment][col]

    const int nColBlocks = B * 16;     // W/32 column tiles per image

    if ((int)blockIdx.x < nColBlocks) {
        // ----- column scan (channel 1), single pass, 16 rows/thread -----
        const int tile = blockIdx.x & 15;        // 16 column-tiles of 32
        const int b    = blockIdx.x >> 4;
        const int cx   = threadIdx.x & 31;       // column within tile
        const int seg  = threadIdx.x >> 5;       // 0..31 (16-row segments)
        const int col  = tile * 32 + cx;

        const size_t base = (size_t)b * (2 * W * W) + (size_t)(W * W) + col;
        const float* __restrict__ p = in  + base + (size_t)(seg * 16) * W;
        float*       __restrict__ q = out + base + (size_t)(seg * 16) * W;

        float v[16];
#pragma unroll
        for (int y = 0; y < 16; ++y) v[y] = p[(size_t)y * W];

        float acc = 0.f;
#pragma unroll
        for (int y = 0; y < 16; ++y) { acc += v[y]; v[y] = acc; }

        sums[seg][cx] = acc;
        __syncthreads();

        float off = 0.f;
        for (int s = 0; s < seg; ++s) off += sums[s][cx];

#pragma unroll
        for (int y = 0; y < 16; ++y) q[(size_t)y * W] = v[y] + off;
    } else {
        // ----- row scan (channel 0) -----
        const int tx  = threadIdx.x & 63;        // lane
        const int wv  = threadIdx.x >> 6;        // wave 0..15
        const int rb  = (int)blockIdx.x - nColBlocks;
        const int row = rb * 16 + wv;            // global row in [0, B*W)
        const int b   = row >> 9;                // / 512
        const int y   = row & 511;               // % 512
        const size_t base = (size_t)b * (2 * W * W) + (size_t)y * W;

        const float4* __restrict__ ip = (const float4*)(in + base);
        float4 v0 = ip[tx * 2 + 0];
        float4 v1 = ip[tx * 2 + 1];

        float a0 = v0.x;
        float a1 = a0 + v0.y;
        float a2 = a1 + v0.z;
        float a3 = a2 + v0.w;
        float a4 = a3 + v1.x;
        float a5 = a4 + v1.y;
        float a6 = a5 + v1.z;
        float a7 = a6 + v1.w;

        float total = a7;
        float inc = total;
#pragma unroll
        for (int o = 1; o < 64; o <<= 1) {
            float t = __shfl_up(inc, o, 64);
            if (tx >= o) inc += t;
        }
        const float excl = inc - total;

        float4 r0 = make_float4(a0 + excl, a1 + excl, a2 + excl, a3 + excl);
        float4 r1 = make_float4(a4 + excl, a5 + excl, a6 + excl, a7 + excl);

        float4* __restrict__ op = (float4*)(out + base);
        op[tx * 2 + 0] = r0;
        op[tx * 2 + 1] = r1;
    }
}

extern "C" void kernel_launch(void* const* d_in, const int* in_sizes, int n_in,
                              void* d_out, int out_size, void* d_ws, size_t ws_size,
                              hipStream_t stream) {
    const float* in = (const float*)d_in[0];
    float* out = (float*)d_out;

    const int B = in_sizes[0] / (2 * W * W);   // 64
    const int colBlocks = B * 16;              // 1024 (32-col tiles)
    const int rowBlocks = (B * W) / 16;        // 2048 (16 rows per block)

    fused_scan_kernel<<<colBlocks + rowBlocks, 1024, 0, stream>>>(in, out, B);
}

// Round 5
// 43.536 us; speedup vs baseline: 1.0359x; 1.0359x over previous
//
#include <hip/hip_runtime.h>

#define W 512

// ---------------------------------------------------------------------------
// Fused kernel, 1024 threads = 16 waves per block.
//
// Blocks [0, B*4):  column scan (channel 1), float4-vectorized, explicit
//   2-pass. Tile = 128 cols x 512 rows. Thread (c4 = t&31, seg = t>>5)
//   owns columns [4*c4, 4*c4+4) x rows [16*seg, 16*seg+16).
//   Phase 1: 16 strided float4 loads -> segment sum (only acc4 live).
//   LDS exchange of segment sums; exclusive offset per column.
//   Phase 2: reload (L2/L3-hot), rescan with offset as running acc, store.
//   Each wave-level load/store = 2 x 512 B contiguous chunks.
//
// Blocks [B*4, ...): row scan (channel 0). One wave per 512-float row.
//   Lane l owns elements [8l, 8l+8) via 2x float4; local scan of 8 +
//   6-step __shfl_up wave scan.
// ---------------------------------------------------------------------------
__global__ __launch_bounds__(1024) void fused_scan_kernel(const float* __restrict__ in,
                                                          float* __restrict__ out,
                                                          int B) {
    __shared__ float4 sums[32][32];    // [segment][c4]  (16 KiB)

    const int nColBlocks = B * 4;      // 128-col tiles per image

    if ((int)blockIdx.x < nColBlocks) {
        // ----- column scan (channel 1) -----
        const int tile = blockIdx.x & 3;
        const int b    = blockIdx.x >> 2;
        const int c4   = threadIdx.x & 31;     // float4 column group
        const int seg  = threadIdx.x >> 5;     // 0..31, 16 rows each
        const int col  = tile * 128 + c4 * 4;

        const size_t base = (size_t)b * (2 * W * W) + (size_t)(W * W) + col
                          + (size_t)(seg * 16) * W;
        const float4* __restrict__ p = (const float4*)(in + base);
        float4*       __restrict__ q = (float4*)(out + base);
        const int strideV = W / 4;             // row stride in float4 units

        // Phase 1: segment sum (loads consumed immediately -> low VGPR, high MLP)
        float4 acc = make_float4(0.f, 0.f, 0.f, 0.f);
#pragma unroll
        for (int y = 0; y < 16; ++y) {
            float4 t = p[(size_t)y * strideV];
            acc.x += t.x; acc.y += t.y; acc.z += t.z; acc.w += t.w;
        }
        sums[seg][c4] = acc;
        __syncthreads();

        // Exclusive offset = sum of preceding segments' totals
        float4 off = make_float4(0.f, 0.f, 0.f, 0.f);
        for (int s = 0; s < seg; ++s) {
            float4 t = sums[s][c4];
            off.x += t.x; off.y += t.y; off.z += t.z; off.w += t.w;
        }

        // Phase 2: reload (L2/L3-hot), running-scan with offset, store
#pragma unroll
        for (int y = 0; y < 16; ++y) {
            float4 t = p[(size_t)y * strideV];
            off.x += t.x; off.y += t.y; off.z += t.z; off.w += t.w;
            q[(size_t)y * strideV] = off;
        }
    } else {
        // ----- row scan (channel 0) -----
        const int tx  = threadIdx.x & 63;      // lane
        const int wv  = threadIdx.x >> 6;      // wave 0..15
        const int rb  = (int)blockIdx.x - nColBlocks;
        const int row = rb * 16 + wv;          // global row in [0, B*W)
        const int b   = row >> 9;              // / 512
        const int y   = row & 511;             // % 512
        const size_t base = (size_t)b * (2 * W * W) + (size_t)y * W;

        const float4* __restrict__ ip = (const float4*)(in + base);
        float4 v0 = ip[tx * 2 + 0];
        float4 v1 = ip[tx * 2 + 1];

        float a0 = v0.x;
        float a1 = a0 + v0.y;
        float a2 = a1 + v0.z;
        float a3 = a2 + v0.w;
        float a4 = a3 + v1.x;
        float a5 = a4 + v1.y;
        float a6 = a5 + v1.z;
        float a7 = a6 + v1.w;

        float total = a7;
        float inc = total;
#pragma unroll
        for (int o = 1; o < 64; o <<= 1) {
            float t = __shfl_up(inc, o, 64);
            if (tx >= o) inc += t;
        }
        const float excl = inc - total;

        float4 r0 = make_float4(a0 + excl, a1 + excl, a2 + excl, a3 + excl);
        float4 r1 = make_float4(a4 + excl, a5 + excl, a6 + excl, a7 + excl);

        float4* __restrict__ op = (float4*)(out + base);
        op[tx * 2 + 0] = r0;
        op[tx * 2 + 1] = r1;
    }
}

extern "C" void kernel_launch(void* const* d_in, const int* in_sizes, int n_in,
                              void* d_out, int out_size, void* d_ws, size_t ws_size,
                              hipStream_t stream) {
    const float* in = (const float*)d_in[0];
    float* out = (float*)d_out;

    const int B = in_sizes[0] / (2 * W * W);   // 64
    const int colBlocks = B * 4;               // 256  (128-col float4 tiles)
    const int rowBlocks = (B * W) / 16;        // 2048 (16 rows per block)

    fused_scan_kernel<<<colBlocks + rowBlocks, 1024, 0, stream>>>(in, out, B);
}